// Round 16
// baseline (437.447 us; speedup 1.0000x reference)
//
#include <hip/hip_runtime.h>
#include <stdint.h>

typedef unsigned short u16;
typedef uint32_t u32;
typedef __attribute__((ext_vector_type(8))) short short8;
typedef __attribute__((ext_vector_type(4))) float f32x4;
typedef __attribute__((ext_vector_type(4))) u32 u32x4;
typedef __attribute__((ext_vector_type(2))) u32 u32x2;
typedef __attribute__((ext_vector_type(4))) unsigned short u16x4;

#define BS_ 4096   // B*S rows
#define S_ 2048
#define HID_ 2048

__device__ __forceinline__ float bf2f(u16 u) { union { u32 i; float f; } v; v.i = ((u32)u) << 16; return v.f; }
__device__ __forceinline__ u16 f2bf(float f) {
  union { float f; u32 i; } v; v.f = f;
  u32 r = v.i + 0x7fffu + ((v.i >> 16) & 1u);
  return (u16)(r >> 16);
}

__device__ __forceinline__ void gload16(const void* gsrc, void* ldst) {
  __builtin_amdgcn_global_load_lds(
      (const __attribute__((address_space(1))) void*)gsrc,
      (__attribute__((address_space(3))) void*)ldst, 16, 0, 0);
}

// ---------------- fused prep: x->bf16, 6 weight transposes, rope table, bias concat ----------------
__global__ __launch_bounds__(256) void prep(const float* __restrict__ x, u16* __restrict__ xb,
                                            const float* __restrict__ W_dkv, const float* __restrict__ W_dq,
                                            const float* __restrict__ W_uk, const float* __restrict__ W_uv,
                                            const float* __restrict__ W_uq, const float* __restrict__ W_o,
                                            u16* __restrict__ WdkvqT, u16* __restrict__ WukvT,
                                            u16* __restrict__ WuqT, u16* __restrict__ WoT,
                                            const float* __restrict__ b_dkv, const float* __restrict__ b_dq,
                                            const float* __restrict__ b_uk, const float* __restrict__ b_uv,
                                            float* __restrict__ cs, float* __restrict__ bc1,
                                            float* __restrict__ bc2) {
  __shared__ float tile[64][65];
  int b = blockIdx.x;
  const int t = threadIdx.x;
  if (b < 8192) {
    int i = b * 256 + t;
    float4 v = ((const float4*)x)[i];
    u16x4 o;
    o.x = f2bf(v.x); o.y = f2bf(v.y); o.z = f2bf(v.z); o.w = f2bf(v.w);
    ((u16x4*)xb)[i] = o;
    return;
  }
  b -= 8192;
  if (b < 3328) {
    const float* W; u16* WT; int K, N, gx, r = b;
    if (r < 256)                 { W = W_dkv; WT = WdkvqT;                    K = 2048; N = 512;  gx = 8;  }
    else if ((r -= 256) < 768)   { W = W_dq;  WT = WdkvqT + (size_t)512 * 2048; K = 2048; N = 1536; gx = 24; }
    else if ((r -= 768) < 256)   { W = W_uk;  WT = WukvT;                     K = 512;  N = 2048; gx = 32; }
    else if ((r -= 256) < 256)   { W = W_uv;  WT = WukvT + (size_t)2048 * 512;  K = 512;  N = 2048; gx = 32; }
    else if ((r -= 256) < 768)   { W = W_uq;  WT = WuqT;                      K = 1536; N = 2048; gx = 32; }
    else                         { r -= 768;  W = W_o; WT = WoT;              K = 2048; N = 2048; gx = 32; }
    const int nb = (r % gx) * 64, kb = (r / gx) * 64;
#pragma unroll
    for (int c = 0; c < 4; ++c) {
      int idx = c * 256 + t;
      int row = idx >> 4;
      int col4 = (idx & 15) * 4;
      float4 v = *(const float4*)&W[(size_t)(kb + row) * N + nb + col4];
      tile[row][col4 + 0] = v.x; tile[row][col4 + 1] = v.y;
      tile[row][col4 + 2] = v.z; tile[row][col4 + 3] = v.w;
    }
    __syncthreads();
#pragma unroll
    for (int c = 0; c < 4; ++c) {
      int idx = c * 256 + t;
      int n = idx >> 4;
      int k4 = (idx & 15) * 4;
      u16x4 o;
      o.x = f2bf(tile[k4 + 0][n]); o.y = f2bf(tile[k4 + 1][n]);
      o.z = f2bf(tile[k4 + 2][n]); o.w = f2bf(tile[k4 + 3][n]);
      *(u16x4*)&WT[(size_t)(nb + n) * K + kb + k4] = o;
    }
    return;
  }
  b -= 3328;
  if (b < 512) {
    int idx = b * 256 + t;
    int pos = idx >> 6, i = idx & 63;
    float inv = powf(10000.f, -(float)i / 64.f);
    float a = (float)pos * inv;
    cs[idx * 2] = cosf(a);
    cs[idx * 2 + 1] = sinf(a);
    return;
  }
  b -= 512;
  {
    int i = b * 256 + t;
    if (i < 512) bc1[i] = b_dkv[i];
    else if (i < 2048) bc1[i] = b_dq[i - 512];
    else if (i < 4096) bc2[i - 2048] = b_uk[i - 2048];
    else if (i < 6144) bc2[i - 2048] = b_uv[i - 4096];
  }
}

// ---------------- GEMM (double-buffered single-barrier K-loop, swapped epilogue, XCD swizzle) ----------------
template <int OUTF32>
__global__ __launch_bounds__(256) void gemm_bt(const u16* __restrict__ A, int lda,
                                               const u16* __restrict__ BT,
                                               const float* __restrict__ bias,
                                               void* __restrict__ Cout,
                                               int M, int N, int K) {
  __shared__ u16 As[2][128 * 64];
  __shared__ u16 Bs[2][128 * 64];
  const int t = threadIdx.x;
  const int lane = t & 63, wave = t >> 6;
  const int wm = wave >> 1, wn = wave & 1;
  const int gx = gridDim.x;
  const int nwg = gx * gridDim.y;
  const int flat = blockIdx.y * gx + blockIdx.x;
  const int swz = (flat & 7) * (nwg >> 3) + (flat >> 3);
  const int tn = swz % gx, tm = swz / gx;
  const int r16 = lane & 15, q4 = lane >> 4;

  f32x4 acc[4][4];
#pragma unroll
  for (int m = 0; m < 4; ++m)
#pragma unroll
    for (int n = 0; n < 4; ++n) acc[m][n] = (f32x4){0.f, 0.f, 0.f, 0.f};

  auto stg = [&](int bufi, int kt) {
#pragma unroll
    for (int c = 0; c < 4; ++c) {
      int idx = c * 256 + t;
      int row = idx >> 3, ch = idx & 7;
      gload16(&A[(size_t)(tm * 128 + row) * lda + kt + ch * 8], (char*)As[bufi] + idx * 16);
      gload16(&BT[(size_t)(tn * 128 + row) * K + kt + ch * 8], (char*)Bs[bufi] + idx * 16);
    }
  };

  const int nkt = K >> 6;
  stg(0, 0);
  __syncthreads();
  for (int it = 0; it < nkt; ++it) {
    const int buf = it & 1;
    if (it + 1 < nkt) stg(buf ^ 1, (it + 1) << 6);
#pragma unroll
    for (int kk = 0; kk < 64; kk += 32) {
      short8 af[4], bfv[4];
#pragma unroll
      for (int m = 0; m < 4; ++m)
        af[m] = *(const short8*)&As[buf][(wm * 64 + m * 16 + r16) * 64 + kk + q4 * 8];
#pragma unroll
      for (int n = 0; n < 4; ++n)
        bfv[n] = *(const short8*)&Bs[buf][(wn * 64 + n * 16 + r16) * 64 + kk + q4 * 8];
      __builtin_amdgcn_s_setprio(1);
#pragma unroll
      for (int m = 0; m < 4; ++m)
#pragma unroll
        for (int n = 0; n < 4; ++n)
          acc[m][n] = __builtin_amdgcn_mfma_f32_16x16x32_bf16(bfv[n], af[m], acc[m][n], 0, 0, 0);
      __builtin_amdgcn_s_setprio(0);
    }
    __syncthreads();
  }
#pragma unroll
  for (int n = 0; n < 4; ++n) {
    int gc0 = tn * 128 + wn * 64 + n * 16 + q4 * 4;
    float4 bv4 = *(const float4*)&bias[gc0];
#pragma unroll
    for (int m = 0; m < 4; ++m) {
      int grow = tm * 128 + wm * 64 + m * 16 + r16;
      float v0 = acc[m][n][0] + bv4.x, v1 = acc[m][n][1] + bv4.y;
      float v2 = acc[m][n][2] + bv4.z, v3 = acc[m][n][3] + bv4.w;
      if (OUTF32) {
        float4 o; o.x = v0; o.y = v1; o.z = v2; o.w = v3;
        *(float4*)&((float*)Cout)[(size_t)grow * N + gc0] = o;
      } else {
        u16x4 o; o.x = f2bf(v0); o.y = f2bf(v1); o.z = f2bf(v2); o.w = f2bf(v3);
        *(u16x4*)&((u16*)Cout)[(size_t)grow * N + gc0] = o;
      }
    }
  }
}

// ---------------- merged GEMM2+GEMM3 v4: dbuf single-barrier K-loop, contiguous long-first grid ----------------
__global__ __launch_bounds__(256) void gemm23(const u16* __restrict__ kvq1,
                                              const u16* __restrict__ WukvT, const u16* __restrict__ WuqT,
                                              const float* __restrict__ bc2, const float* __restrict__ b_uq,
                                              const float* __restrict__ cs,
                                              u16* __restrict__ kbuf, u16* __restrict__ VT,
                                              u16* __restrict__ qb) {
  __shared__ u16 sh[4 * 128 * 64];   // 64KB: per-buf As(16KB)|Bs(16KB); first 32KB reused as transpose buffer
  const int t = threadIdx.x;
  const int lane = t & 63, wave = t >> 6;
  const int wm = wave >> 1, wn = wave & 1;
  const int bflat = blockIdx.x;
  const bool g2 = (bflat >= 512);          // GEMM3 occupies blocks 0..511, contiguous per problem
  const u16* A  = g2 ? kvq1 : (kvq1 + 512);
  const u16* BT = g2 ? WukvT : WuqT;
  const float* bias = g2 ? bc2 : b_uq;
  const int K = g2 ? 512 : 1536;
  const int gx = g2 ? 32 : 16;
  const int nwg = g2 ? 1024 : 512;
  const int flat = g2 ? (bflat - 512) : bflat;
  const int swz = (flat & 7) * (nwg >> 3) + (flat >> 3);
  const int tn = swz % gx, tm = swz / gx;
  const int r16 = lane & 15, q4 = lane >> 4;

  f32x4 acc[4][4];
#pragma unroll
  for (int m = 0; m < 4; ++m)
#pragma unroll
    for (int n = 0; n < 4; ++n) acc[m][n] = (f32x4){0.f, 0.f, 0.f, 0.f};

  auto stg = [&](int bufi, int kt) {
    char* Asb = (char*)(sh + bufi * 16384);
    char* Bsb = Asb + 16384;
#pragma unroll
    for (int c = 0; c < 4; ++c) {
      int idx = c * 256 + t;
      int row = idx >> 3, ch = idx & 7;
      gload16(&A[(size_t)(tm * 128 + row) * 2048 + kt + ch * 8], Asb + idx * 16);
      gload16(&BT[(size_t)(tn * 128 + row) * K + kt + ch * 8], Bsb + idx * 16);
    }
  };

  const int nkt = K >> 6;
  stg(0, 0);
  __syncthreads();
  for (int it = 0; it < nkt; ++it) {
    const int buf = it & 1;
    if (it + 1 < nkt) stg(buf ^ 1, (it + 1) << 6);
    const u16* As = sh + buf * 16384;
    const u16* Bs = As + 8192;
#pragma unroll
    for (int kk = 0; kk < 64; kk += 32) {
      short8 af[4], bfv[4];
#pragma unroll
      for (int m = 0; m < 4; ++m)
        af[m] = *(const short8*)&As[(wm * 64 + m * 16 + r16) * 64 + kk + q4 * 8];
#pragma unroll
      for (int n = 0; n < 4; ++n)
        bfv[n] = *(const short8*)&Bs[(wn * 64 + n * 16 + r16) * 64 + kk + q4 * 8];
      __builtin_amdgcn_s_setprio(1);
#pragma unroll
      for (int m = 0; m < 4; ++m)
#pragma unroll
        for (int n = 0; n < 4; ++n)
          acc[m][n] = __builtin_amdgcn_mfma_f32_16x16x32_bf16(bfv[n], af[m], acc[m][n], 0, 0, 0);
      __builtin_amdgcn_s_setprio(0);
    }
    __syncthreads();
  }

  const bool isV = g2 && (tn >= 16);
  if (!isV) {
    u16* outp = g2 ? kbuf : qb;
#pragma unroll
    for (int n = 0; n < 4; ++n) {
      int gc0 = tn * 128 + wn * 64 + n * 16 + q4 * 4;
      float4 bv4 = *(const float4*)&bias[gc0];
      const int i0 = (gc0 & 127) >> 1;
#pragma unroll
      for (int m = 0; m < 4; ++m) {
        int grow = tm * 128 + wm * 64 + m * 16 + r16;
        float v0 = acc[m][n][0] + bv4.x, v1 = acc[m][n][1] + bv4.y;
        float v2 = acc[m][n][2] + bv4.z, v3 = acc[m][n][3] + bv4.w;
        int s = grow & 2047;
        float4 cp = *(const float4*)&cs[((size_t)s * 64 + i0) * 2];   // c0,s0,c1,s1
        float y0 = v0 * cp.x - v1 * cp.y;
        float y1 = v0 * cp.y + v1 * cp.x;
        float y2 = v2 * cp.z - v3 * cp.w;
        float y3 = v2 * cp.w + v3 * cp.z;
        u16x4 o; o.x = f2bf(y0); o.y = f2bf(y1); o.z = f2bf(y2); o.w = f2bf(y3);
        *(u16x4*)&outp[(size_t)grow * 2048 + gc0] = o;
      }
    }
  } else {
    u16* lt = sh;
    __syncthreads();   // all waves done reading K-loop LDS before overwrite
#pragma unroll
    for (int n = 0; n < 4; ++n) {
      int gc0 = tn * 128 + wn * 64 + n * 16 + q4 * 4;
      float4 bv4 = *(const float4*)&bias[gc0];
      int dL0 = wn * 64 + n * 16 + q4 * 4;
#pragma unroll
      for (int m = 0; m < 4; ++m) {
        int sL = wm * 64 + m * 16 + r16;
        float vv[4] = {acc[m][n][0] + bv4.x, acc[m][n][1] + bv4.y,
                       acc[m][n][2] + bv4.z, acc[m][n][3] + bv4.w};
#pragma unroll
        for (int j = 0; j < 4; ++j) {
          int dd = dL0 + j;
          lt[dd * 128 + (sL ^ ((dd & 7) << 4))] = f2bf(vv[j]);
        }
      }
    }
    __syncthreads();
    const int hh = tn - 16;
    const int bb2 = tm >> 4;
    const int s0 = (tm & 15) * 128;
    u16* vbase = VT + (size_t)(bb2 * 16 + hh) * 128 * S_ + s0;
#pragma unroll
    for (int c = 0; c < 8; ++c) {
      int idx = c * 256 + t;
      int d = idx >> 4, ch = idx & 15;
      short8 v = *(const short8*)&lt[d * 128 + ((ch * 8) ^ ((d & 7) << 4))];
      *(short8*)&vbase[(size_t)d * S_ + ch * 8] = v;
    }
  }
}

// ---------------- causal flash attention v10: 1024 blocks, V from global/L2, 3 blocks/CU ----------------
// b: xcd=b&7, i=(b>>3)&31, g=b>>8; qt=31-i (longest-first), bh=g*8+xcd (XCD-pinned heads).
// Block = one 64-row q-tile. 4 waves: par=w>>1 (even/odd 32-kv tiles), sub=w&1 (q-half, 32 rows M=2).
// K staged to LDS (both parities, dbuf across rounds); V^T read directly from global (L2-resident).
// Parity partials merged in-block via LDS (2 passes over m).
__global__ __launch_bounds__(256, 3) void attn_kernel(const u16* __restrict__ Q, const u16* __restrict__ K,
                                                      int kld, const u16* __restrict__ VT,
                                                      u16* __restrict__ O) {
  __shared__ char smem[43008];
  u16* Kl = (u16*)smem;                 // 4 bufs (2 rounds x 2 par) x [32][128] swizzled = 32KB
  u16* Pl = (u16*)(smem + 32768);       // 4 waves x [32 rows][80B] = 10240B
  float* ex = (float*)smem;             // merge overlay, 17408B per pass (K dead)

  const int t = threadIdx.x;
  const int lane = t & 63, w = t >> 6;
  const int r16 = lane & 15, q4 = lane >> 4;
  const int par = w >> 1, sub = w & 1;
  const int b = blockIdx.x;
  const int xcd = b & 7, i = (b >> 3) & 31, g = b >> 8;
  const int qt = 31 - i;
  const int bh = g * 8 + xcd;
  const int bb = bh >> 4, h = bh & 15;
  const u16* Qb = Q + (size_t)bb * S_ * HID_ + (size_t)h * 128;
  const u16* Kb = K + (size_t)bb * S_ * kld + (size_t)h * 128;
  const u16* VTb = VT + (size_t)bh * 128 * S_;
  u16* Ob = O + (size_t)bb * S_ * HID_ + (size_t)h * 128;

  auto stageK = [&](int rs, int kvbase) {
#pragma unroll
    for (int pp = 0; pp < 2; ++pp) {
      int kvb = kvbase + pp * 32;
      char* kd = (char*)(Kl + (size_t)(rs * 2 + pp) * 4096);
#pragma unroll
      for (int c = 0; c < 2; ++c) {
        int s = c * 256 + t;
        int row = s >> 4;
        int ch = (s & 15) ^ (row & 7);
        gload16(&Kb[(size_t)(kvb + row) * kld + ch * 8], kd + s * 16);
      }
    }
  };

  u16* Pw = Pl + (size_t)w * 1280;
  const float SCALE = 0.08838834764831845f;

  const int nr = qt + 1;
  const int qrow0 = qt * 64 + sub * 32;

  short8 qf[2][4];
#pragma unroll
  for (int m = 0; m < 2; ++m)
#pragma unroll
    for (int dk = 0; dk < 4; ++dk)
      qf[m][dk] = *(const short8*)&Qb[(size_t)(qrow0 + m * 16 + r16) * HID_ + dk * 32 + q4 * 8];

  f32x4 ao[2][8];
  float mr[2], lr[2];
#pragma unroll
  for (int m = 0; m < 2; ++m) {
#pragma unroll
    for (int dn = 0; dn < 8; ++dn) ao[m][dn] = (f32x4){0.f, 0.f, 0.f, 0.f};
    mr[m] = -1e30f; lr[m] = 0.f;
  }

  stageK(0, 0);
  __syncthreads();

  for (int r = 0; r < nr; ++r) {
    const int rs = r & 1;
    if (r + 1 < nr) stageK(rs ^ 1, (r + 1) * 64);
    const int kv0 = r * 64 + par * 32;
    const u16* Kbuf = Kl + (size_t)(rs * 2 + par) * 4096;

    if (kv0 <= qrow0 + 31) {
      // ---- V^T fragment loads from global (L2), batch-issued early ----
      short8 vf[8];
#pragma unroll
      for (int dn = 0; dn < 8; ++dn)
        vf[dn] = *(const short8*)&VTb[(size_t)(dn * 16 + r16) * S_ + kv0 + q4 * 8];
      // ---- QK^T swapped ----
      f32x4 sc[2][2];
#pragma unroll
      for (int m = 0; m < 2; ++m)
#pragma unroll
        for (int n = 0; n < 2; ++n) sc[m][n] = (f32x4){0.f, 0.f, 0.f, 0.f};
#pragma unroll
      for (int dk = 0; dk < 4; ++dk) {
        short8 kf[2];
#pragma unroll
        for (int n = 0; n < 2; ++n) {
          int kr = n * 16 + r16;
          int ba = (kr * 256 + dk * 64 + q4 * 16) ^ ((kr & 7) << 4);
          kf[n] = *(const short8*)((const char*)Kbuf + ba);
        }
        __builtin_amdgcn_s_setprio(1);
#pragma unroll
        for (int n = 0; n < 2; ++n)
#pragma unroll
          for (int m = 0; m < 2; ++m)
            sc[m][n] = __builtin_amdgcn_mfma_f32_16x16x32_bf16(kf[n], qf[m][dk], sc[m][n], 0, 0, 0);
        __builtin_amdgcn_s_setprio(0);
      }
      // ---- scale + causal mask ----
      const bool nm = (kv0 + 31 > qrow0);
#pragma unroll
      for (int m = 0; m < 2; ++m) {
        const int q = qrow0 + m * 16 + r16;
#pragma unroll
        for (int n = 0; n < 2; ++n)
#pragma unroll
          for (int j = 0; j < 4; ++j) {
            float sv = sc[m][n][j] * SCALE;
            if (nm) {
              int kv = kv0 + n * 16 + q4 * 4 + j;
              if (kv > q) sv = -1e30f;
            }
            sc[m][n][j] = sv;
          }
      }
      // ---- online softmax per m, joint defer-max ----
      float tm0[2];
#pragma unroll
      for (int m = 0; m < 2; ++m) {
        float tm = sc[m][0][0];
#pragma unroll
        for (int n = 0; n < 2; ++n)
#pragma unroll
          for (int j = 0; j < 4; ++j) tm = fmaxf(tm, sc[m][n][j]);
        tm = fmaxf(tm, __shfl_xor(tm, 16));
        tm = fmaxf(tm, __shfl_xor(tm, 32));
        tm0[m] = tm;
      }
      float growth = fmaxf(tm0[0] - mr[0], tm0[1] - mr[1]);
      if (!__all(growth <= 8.0f)) {
#pragma unroll
        for (int m = 0; m < 2; ++m) {
          float mnew = fmaxf(mr[m], tm0[m]);
          float fsc = __expf(mr[m] - mnew);
          lr[m] *= fsc; mr[m] = mnew;
#pragma unroll
          for (int dn = 0; dn < 8; ++dn) ao[m][dn] *= fsc;
        }
      }
#pragma unroll
      for (int m = 0; m < 2; ++m) {
        float ps = 0.f;
#pragma unroll
        for (int n = 0; n < 2; ++n)
#pragma unroll
          for (int j = 0; j < 4; ++j) {
            float pv = __expf(sc[m][n][j] - mr[m]);
            sc[m][n][j] = pv;
            ps += pv;
          }
        ps += __shfl_xor(ps, 16);
        ps += __shfl_xor(ps, 32);
        lr[m] += ps;
      }
      // ---- P -> LDS ----
#pragma unroll
      for (int m = 0; m < 2; ++m)
#pragma unroll
        for (int n = 0; n < 2; ++n) {
          u32 lo, hi;
          asm("v_cvt_pk_bf16_f32 %0, %1, %2" : "=v"(lo) : "v"(sc[m][n][0]), "v"(sc[m][n][1]));
          asm("v_cvt_pk_bf16_f32 %0, %1, %2" : "=v"(hi) : "v"(sc[m][n][2]), "v"(sc[m][n][3]));
          u32x2 pr; pr.x = lo; pr.y = hi;
          int ba = (m * 16 + r16) * 80 + n * 32 + q4 * 8;
          *(u32x2*)((char*)Pw + ba) = pr;
        }
      // ---- PV: mfma(A=vf from global, B=pb) ----
      short8 pb[2];
#pragma unroll
      for (int m = 0; m < 2; ++m)
        pb[m] = *(const short8*)((const char*)Pw + (m * 16 + r16) * 80 + q4 * 16);
      __builtin_amdgcn_s_setprio(1);
#pragma unroll
      for (int dn = 0; dn < 8; ++dn)
#pragma unroll
        for (int m = 0; m < 2; ++m)
          ao[m][dn] = __builtin_amdgcn_mfma_f32_16x16x32_bf16(vf[dn], pb[m], ao[m][dn], 0, 0, 0);
      __builtin_amdgcn_s_setprio(0);
    }
    __syncthreads();   // next round's K DMA landed; buffers safe to swap
  }

  // ---- in-block merge of parity partials (2 passes over m; overlay on dead K region) ----
#pragma unroll
  for (int mp = 0; mp < 2; ++mp) {
    float* exb = ex + (size_t)(sub * 64 + lane) * 34;
    if (par == 1) {
#pragma unroll
      for (int dn = 0; dn < 8; ++dn)
        *(f32x4*)(exb + dn * 4) = ao[mp][dn];
      exb[32] = mr[mp]; exb[33] = lr[mp];
    }
    __syncthreads();
    if (par == 0) {
      float mB = exb[32], lB = exb[33];
      float mx = fmaxf(mr[mp], mB);
      float wA = __expf(mr[mp] - mx), wB = __expf(mB - mx);
      float inv = 1.f / (lr[mp] * wA + lB * wB);
      const int q = qrow0 + mp * 16 + r16;
#pragma unroll
      for (int dn = 0; dn < 8; ++dn) {
        f32x4 ob = *(const f32x4*)(exb + dn * 4);
        u16x4 o;
#pragma unroll
        for (int j = 0; j < 4; ++j) o[j] = f2bf((ao[mp][dn][j] * wA + ob[j] * wB) * inv);
        *(u16x4*)&Ob[(size_t)q * HID_ + dn * 16 + q4 * 4] = o;
      }
    }
    __syncthreads();
  }
}

// ---------------- host launch ----------------
extern "C" void kernel_launch(void* const* d_in, const int* in_sizes, int n_in,
                              void* d_out, int out_size, void* d_ws, size_t ws_size,
                              hipStream_t stream) {
  (void)in_sizes; (void)n_in; (void)out_size; (void)ws_size;
  const float* x     = (const float*)d_in[0];
  const float* W_dkv = (const float*)d_in[2];
  const float* b_dkv = (const float*)d_in[3];
  const float* W_uk  = (const float*)d_in[4];
  const float* b_uk  = (const float*)d_in[5];
  const float* W_uv  = (const float*)d_in[6];
  const float* b_uv  = (const float*)d_in[7];
  const float* W_dq  = (const float*)d_in[8];
  const float* b_dq  = (const float*)d_in[9];
  const float* W_uq  = (const float*)d_in[10];
  const float* b_uq  = (const float*)d_in[11];
  const float* W_o   = (const float*)d_in[12];
  const float* b_o   = (const float*)d_in[13];
  float* out = (float*)d_out;

  char* ws = (char*)d_ws;
  size_t off = 0;
  auto carve = [&](size_t bytes) { void* p = ws + off; off += (bytes + 255) & ~(size_t)255; return p; };
  u16* xb     = (u16*)carve((size_t)BS_ * 2048 * 2);      // reused as VT after GEMM1
  u16* WdkvqT = (u16*)carve((size_t)2048 * 2048 * 2);
  u16* WukvT  = (u16*)carve((size_t)4096 * 512 * 2);
  u16* WuqT   = (u16*)carve((size_t)2048 * 1536 * 2);
  u16* WoT    = (u16*)carve((size_t)2048 * 2048 * 2);
  u16* kvq1   = (u16*)carve((size_t)BS_ * 2048 * 2);
  u16* kbuf   = (u16*)carve((size_t)BS_ * 2048 * 2);
  u16* qb     = (u16*)carve((size_t)BS_ * 2048 * 2);
  u16* aob    = (u16*)carve((size_t)BS_ * 2048 * 2);
  float* cs   = (float*)carve((size_t)2048 * 64 * 2 * 4);
  float* bc1  = (float*)carve((size_t)2048 * 4);
  float* bc2  = (float*)carve((size_t)4096 * 4);
  u16* VT     = xb;   // xb dead after GEMM1; V^T [32][128][2048]

  prep<<<dim3(12056), 256, 0, stream>>>(x, xb, W_dkv, W_dq, W_uk, W_uv, W_uq, W_o,
                                        WdkvqT, WukvT, WuqT, WoT,
                                        b_dkv, b_dq, b_uk, b_uv, cs, bc1, bc2);

  // GEMM1: x @ {W_dkv|W_dq} -> kvq1
  gemm_bt<0><<<dim3(2048 / 128, BS_ / 128), 256, 0, stream>>>(xb, 2048, WdkvqT, bc1, kvq1, BS_, 2048, 2048);

  // GEMM2+GEMM3 merged (contiguous long-first grid, dbuf K-loop)
  gemm23<<<dim3(1536), 256, 0, stream>>>(kvq1, WukvT, WuqT, bc2, b_uq, cs, kbuf, VT, qb);

  attn_kernel<<<dim3(1024), 256, 0, stream>>>(qb, kbuf, 2048, VT, aob);

  // GEMM4: attn_out @ W_o -> out (fp32)
  gemm_bt<1><<<dim3(2048 / 128, BS_ / 128), 256, 0, stream>>>(aob, 2048, WoT, b_o, out, BS_, 2048, 2048);
}

// Round 17
// 258.910 us; speedup vs baseline: 1.6896x; 1.6896x over previous
//
#include <hip/hip_runtime.h>
#include <stdint.h>

typedef unsigned short u16;
typedef uint32_t u32;
typedef __attribute__((ext_vector_type(8))) short short8;
typedef __attribute__((ext_vector_type(4))) float f32x4;
typedef __attribute__((ext_vector_type(4))) u32 u32x4;
typedef __attribute__((ext_vector_type(2))) u32 u32x2;
typedef __attribute__((ext_vector_type(4))) unsigned short u16x4;

#define BS_ 4096   // B*S rows
#define S_ 2048
#define HID_ 2048

__device__ __forceinline__ float bf2f(u16 u) { union { u32 i; float f; } v; v.i = ((u32)u) << 16; return v.f; }
__device__ __forceinline__ u16 f2bf(float f) {
  union { float f; u32 i; } v; v.f = f;
  u32 r = v.i + 0x7fffu + ((v.i >> 16) & 1u);
  return (u16)(r >> 16);
}

__device__ __forceinline__ void gload16(const void* gsrc, void* ldst) {
  __builtin_amdgcn_global_load_lds(
      (const __attribute__((address_space(1))) void*)gsrc,
      (__attribute__((address_space(3))) void*)ldst, 16, 0, 0);
}

// ---------------- fused prep: x->bf16, 6 weight transposes, rope table, bias concat ----------------
__global__ __launch_bounds__(256) void prep(const float* __restrict__ x, u16* __restrict__ xb,
                                            const float* __restrict__ W_dkv, const float* __restrict__ W_dq,
                                            const float* __restrict__ W_uk, const float* __restrict__ W_uv,
                                            const float* __restrict__ W_uq, const float* __restrict__ W_o,
                                            u16* __restrict__ WdkvqT, u16* __restrict__ WukvT,
                                            u16* __restrict__ WuqT, u16* __restrict__ WoT,
                                            const float* __restrict__ b_dkv, const float* __restrict__ b_dq,
                                            const float* __restrict__ b_uk, const float* __restrict__ b_uv,
                                            float* __restrict__ cs, float* __restrict__ bc1,
                                            float* __restrict__ bc2) {
  __shared__ float tile[64][65];
  int b = blockIdx.x;
  const int t = threadIdx.x;
  if (b < 8192) {
    int i = b * 256 + t;
    float4 v = ((const float4*)x)[i];
    u16x4 o;
    o.x = f2bf(v.x); o.y = f2bf(v.y); o.z = f2bf(v.z); o.w = f2bf(v.w);
    ((u16x4*)xb)[i] = o;
    return;
  }
  b -= 8192;
  if (b < 3328) {
    const float* W; u16* WT; int K, N, gx, r = b;
    if (r < 256)                 { W = W_dkv; WT = WdkvqT;                    K = 2048; N = 512;  gx = 8;  }
    else if ((r -= 256) < 768)   { W = W_dq;  WT = WdkvqT + (size_t)512 * 2048; K = 2048; N = 1536; gx = 24; }
    else if ((r -= 768) < 256)   { W = W_uk;  WT = WukvT;                     K = 512;  N = 2048; gx = 32; }
    else if ((r -= 256) < 256)   { W = W_uv;  WT = WukvT + (size_t)2048 * 512;  K = 512;  N = 2048; gx = 32; }
    else if ((r -= 256) < 768)   { W = W_uq;  WT = WuqT;                      K = 1536; N = 2048; gx = 32; }
    else                         { r -= 768;  W = W_o; WT = WoT;              K = 2048; N = 2048; gx = 32; }
    const int nb = (r % gx) * 64, kb = (r / gx) * 64;
#pragma unroll
    for (int c = 0; c < 4; ++c) {
      int idx = c * 256 + t;
      int row = idx >> 4;
      int col4 = (idx & 15) * 4;
      float4 v = *(const float4*)&W[(size_t)(kb + row) * N + nb + col4];
      tile[row][col4 + 0] = v.x; tile[row][col4 + 1] = v.y;
      tile[row][col4 + 2] = v.z; tile[row][col4 + 3] = v.w;
    }
    __syncthreads();
#pragma unroll
    for (int c = 0; c < 4; ++c) {
      int idx = c * 256 + t;
      int n = idx >> 4;
      int k4 = (idx & 15) * 4;
      u16x4 o;
      o.x = f2bf(tile[k4 + 0][n]); o.y = f2bf(tile[k4 + 1][n]);
      o.z = f2bf(tile[k4 + 2][n]); o.w = f2bf(tile[k4 + 3][n]);
      *(u16x4*)&WT[(size_t)(nb + n) * K + kb + k4] = o;
    }
    return;
  }
  b -= 3328;
  if (b < 512) {
    int idx = b * 256 + t;
    int pos = idx >> 6, i = idx & 63;
    float inv = powf(10000.f, -(float)i / 64.f);
    float a = (float)pos * inv;
    cs[idx * 2] = cosf(a);
    cs[idx * 2 + 1] = sinf(a);
    return;
  }
  b -= 512;
  {
    int i = b * 256 + t;
    if (i < 512) bc1[i] = b_dkv[i];
    else if (i < 2048) bc1[i] = b_dq[i - 512];
    else if (i < 4096) bc2[i - 2048] = b_uk[i - 2048];
    else if (i < 6144) bc2[i - 2048] = b_uv[i - 4096];
  }
}

// ---------------- GEMM (double-buffered single-barrier K-loop, swapped epilogue, XCD swizzle) ----------------
template <int OUTF32>
__global__ __launch_bounds__(256) void gemm_bt(const u16* __restrict__ A, int lda,
                                               const u16* __restrict__ BT,
                                               const float* __restrict__ bias,
                                               void* __restrict__ Cout,
                                               int M, int N, int K) {
  __shared__ u16 As[2][128 * 64];
  __shared__ u16 Bs[2][128 * 64];
  const int t = threadIdx.x;
  const int lane = t & 63, wave = t >> 6;
  const int wm = wave >> 1, wn = wave & 1;
  const int gx = gridDim.x;
  const int nwg = gx * gridDim.y;
  const int flat = blockIdx.y * gx + blockIdx.x;
  const int swz = (flat & 7) * (nwg >> 3) + (flat >> 3);
  const int tn = swz % gx, tm = swz / gx;
  const int r16 = lane & 15, q4 = lane >> 4;

  f32x4 acc[4][4];
#pragma unroll
  for (int m = 0; m < 4; ++m)
#pragma unroll
    for (int n = 0; n < 4; ++n) acc[m][n] = (f32x4){0.f, 0.f, 0.f, 0.f};

  auto stg = [&](int bufi, int kt) {
#pragma unroll
    for (int c = 0; c < 4; ++c) {
      int idx = c * 256 + t;
      int row = idx >> 3, ch = idx & 7;
      gload16(&A[(size_t)(tm * 128 + row) * lda + kt + ch * 8], (char*)As[bufi] + idx * 16);
      gload16(&BT[(size_t)(tn * 128 + row) * K + kt + ch * 8], (char*)Bs[bufi] + idx * 16);
    }
  };

  const int nkt = K >> 6;
  stg(0, 0);
  __syncthreads();
  for (int it = 0; it < nkt; ++it) {
    const int buf = it & 1;
    if (it + 1 < nkt) stg(buf ^ 1, (it + 1) << 6);
#pragma unroll
    for (int kk = 0; kk < 64; kk += 32) {
      short8 af[4], bfv[4];
#pragma unroll
      for (int m = 0; m < 4; ++m)
        af[m] = *(const short8*)&As[buf][(wm * 64 + m * 16 + r16) * 64 + kk + q4 * 8];
#pragma unroll
      for (int n = 0; n < 4; ++n)
        bfv[n] = *(const short8*)&Bs[buf][(wn * 64 + n * 16 + r16) * 64 + kk + q4 * 8];
      __builtin_amdgcn_s_setprio(1);
#pragma unroll
      for (int m = 0; m < 4; ++m)
#pragma unroll
        for (int n = 0; n < 4; ++n)
          acc[m][n] = __builtin_amdgcn_mfma_f32_16x16x32_bf16(bfv[n], af[m], acc[m][n], 0, 0, 0);
      __builtin_amdgcn_s_setprio(0);
    }
    __syncthreads();
  }
#pragma unroll
  for (int n = 0; n < 4; ++n) {
    int gc0 = tn * 128 + wn * 64 + n * 16 + q4 * 4;
    float4 bv4 = *(const float4*)&bias[gc0];
#pragma unroll
    for (int m = 0; m < 4; ++m) {
      int grow = tm * 128 + wm * 64 + m * 16 + r16;
      float v0 = acc[m][n][0] + bv4.x, v1 = acc[m][n][1] + bv4.y;
      float v2 = acc[m][n][2] + bv4.z, v3 = acc[m][n][3] + bv4.w;
      if (OUTF32) {
        float4 o; o.x = v0; o.y = v1; o.z = v2; o.w = v3;
        *(float4*)&((float*)Cout)[(size_t)grow * N + gc0] = o;
      } else {
        u16x4 o; o.x = f2bf(v0); o.y = f2bf(v1); o.z = f2bf(v2); o.w = f2bf(v3);
        *(u16x4*)&((u16*)Cout)[(size_t)grow * N + gc0] = o;
      }
    }
  }
}

// ---------------- merged GEMM2+GEMM3 v4: dbuf single-barrier K-loop, contiguous long-first grid ----------------
// blocks 0..511:   GEMM3: kvq1[:, 512:] @ W_uq (K=1536, N=2048), rope, store qb
// blocks 512..1535: GEMM2: kvq1[:, :512] @ {W_uk|W_uv} (K=512, N=4096)
//    tn<16 (k-half): rope + store kbuf; tn>=16 (v-half): LDS-transpose -> coalesced VT store
__global__ __launch_bounds__(256) void gemm23(const u16* __restrict__ kvq1,
                                              const u16* __restrict__ WukvT, const u16* __restrict__ WuqT,
                                              const float* __restrict__ bc2, const float* __restrict__ b_uq,
                                              const float* __restrict__ cs,
                                              u16* __restrict__ kbuf, u16* __restrict__ VT,
                                              u16* __restrict__ qb) {
  __shared__ u16 sh[4 * 128 * 64];   // 64KB: per-buf As(16KB)|Bs(16KB); first 32KB reused as transpose buffer
  const int t = threadIdx.x;
  const int lane = t & 63, wave = t >> 6;
  const int wm = wave >> 1, wn = wave & 1;
  const int bflat = blockIdx.x;
  const bool g2 = (bflat >= 512);          // GEMM3 occupies blocks 0..511, contiguous per problem
  const u16* A  = g2 ? kvq1 : (kvq1 + 512);
  const u16* BT = g2 ? WukvT : WuqT;
  const float* bias = g2 ? bc2 : b_uq;
  const int K = g2 ? 512 : 1536;
  const int gx = g2 ? 32 : 16;
  const int nwg = g2 ? 1024 : 512;
  const int flat = g2 ? (bflat - 512) : bflat;
  const int swz = (flat & 7) * (nwg >> 3) + (flat >> 3);
  const int tn = swz % gx, tm = swz / gx;
  const int r16 = lane & 15, q4 = lane >> 4;

  f32x4 acc[4][4];
#pragma unroll
  for (int m = 0; m < 4; ++m)
#pragma unroll
    for (int n = 0; n < 4; ++n) acc[m][n] = (f32x4){0.f, 0.f, 0.f, 0.f};

  auto stg = [&](int bufi, int kt) {
    char* Asb = (char*)(sh + bufi * 16384);
    char* Bsb = Asb + 16384;
#pragma unroll
    for (int c = 0; c < 4; ++c) {
      int idx = c * 256 + t;
      int row = idx >> 3, ch = idx & 7;
      gload16(&A[(size_t)(tm * 128 + row) * 2048 + kt + ch * 8], Asb + idx * 16);
      gload16(&BT[(size_t)(tn * 128 + row) * K + kt + ch * 8], Bsb + idx * 16);
    }
  };

  const int nkt = K >> 6;
  stg(0, 0);
  __syncthreads();
  for (int it = 0; it < nkt; ++it) {
    const int buf = it & 1;
    if (it + 1 < nkt) stg(buf ^ 1, (it + 1) << 6);
    const u16* As = sh + buf * 16384;
    const u16* Bs = As + 8192;
#pragma unroll
    for (int kk = 0; kk < 64; kk += 32) {
      short8 af[4], bfv[4];
#pragma unroll
      for (int m = 0; m < 4; ++m)
        af[m] = *(const short8*)&As[(wm * 64 + m * 16 + r16) * 64 + kk + q4 * 8];
#pragma unroll
      for (int n = 0; n < 4; ++n)
        bfv[n] = *(const short8*)&Bs[(wn * 64 + n * 16 + r16) * 64 + kk + q4 * 8];
      __builtin_amdgcn_s_setprio(1);
#pragma unroll
      for (int m = 0; m < 4; ++m)
#pragma unroll
        for (int n = 0; n < 4; ++n)
          acc[m][n] = __builtin_amdgcn_mfma_f32_16x16x32_bf16(bfv[n], af[m], acc[m][n], 0, 0, 0);
      __builtin_amdgcn_s_setprio(0);
    }
    __syncthreads();
  }

  const bool isV = g2 && (tn >= 16);
  if (!isV) {
    u16* outp = g2 ? kbuf : qb;
#pragma unroll
    for (int n = 0; n < 4; ++n) {
      int gc0 = tn * 128 + wn * 64 + n * 16 + q4 * 4;
      float4 bv4 = *(const float4*)&bias[gc0];
      const int i0 = (gc0 & 127) >> 1;
#pragma unroll
      for (int m = 0; m < 4; ++m) {
        int grow = tm * 128 + wm * 64 + m * 16 + r16;
        float v0 = acc[m][n][0] + bv4.x, v1 = acc[m][n][1] + bv4.y;
        float v2 = acc[m][n][2] + bv4.z, v3 = acc[m][n][3] + bv4.w;
        int s = grow & 2047;
        float4 cp = *(const float4*)&cs[((size_t)s * 64 + i0) * 2];   // c0,s0,c1,s1
        float y0 = v0 * cp.x - v1 * cp.y;
        float y1 = v0 * cp.y + v1 * cp.x;
        float y2 = v2 * cp.z - v3 * cp.w;
        float y3 = v2 * cp.w + v3 * cp.z;
        u16x4 o; o.x = f2bf(y0); o.y = f2bf(y1); o.z = f2bf(y2); o.w = f2bf(y3);
        *(u16x4*)&outp[(size_t)grow * 2048 + gc0] = o;
      }
    }
  } else {
    // LDS transpose: lt[d][s] (128x128 u16, s XOR-swizzled by (d&7)<<4), then coalesced VT store
    u16* lt = sh;
    __syncthreads();   // all waves done reading K-loop LDS before overwrite
#pragma unroll
    for (int n = 0; n < 4; ++n) {
      int gc0 = tn * 128 + wn * 64 + n * 16 + q4 * 4;
      float4 bv4 = *(const float4*)&bias[gc0];
      int dL0 = wn * 64 + n * 16 + q4 * 4;
#pragma unroll
      for (int m = 0; m < 4; ++m) {
        int sL = wm * 64 + m * 16 + r16;
        float vv[4] = {acc[m][n][0] + bv4.x, acc[m][n][1] + bv4.y,
                       acc[m][n][2] + bv4.z, acc[m][n][3] + bv4.w};
#pragma unroll
        for (int j = 0; j < 4; ++j) {
          int dd = dL0 + j;
          lt[dd * 128 + (sL ^ ((dd & 7) << 4))] = f2bf(vv[j]);
        }
      }
    }
    __syncthreads();
    const int hh = tn - 16;
    const int bb2 = tm >> 4;
    const int s0 = (tm & 15) * 128;
    u16* vbase = VT + (size_t)(bb2 * 16 + hh) * 128 * S_ + s0;
#pragma unroll
    for (int c = 0; c < 8; ++c) {
      int idx = c * 256 + t;
      int d = idx >> 4, ch = idx & 15;
      short8 v = *(const short8*)&lt[d * 128 + ((ch * 8) ^ ((d & 7) << 4))];
      *(short8*)&vbase[(size_t)d * S_ + ch * 8] = v;
    }
  }
}

// ---------------- causal flash attention v9: kv-parity split, M=2 waves, in-block merge ----------------
__global__ __launch_bounds__(256, 2) void attn_kernel(const u16* __restrict__ Q, const u16* __restrict__ K,
                                                      int kld, const u16* __restrict__ VT,
                                                      u16* __restrict__ O) {
  __shared__ char smem[75776];
  u16* Kl = (u16*)smem;
  u16* Vl = (u16*)(smem + 32768);
  u16* Pl = (u16*)(smem + 65536);
  float* ex = (float*)smem;

  const int t = threadIdx.x;
  const int lane = t & 63, w = t >> 6;
  const int r16 = lane & 15, q4 = lane >> 4;
  const int par = w >> 1, sub = w & 1;
  const int b = blockIdx.x;
  const int xcd = b & 7, u = b >> 3;
  const int p = u & 15, g4 = u >> 4;
  const int bh = g4 * 8 + xcd;
  const int bb = bh >> 4, h = bh & 15;
  const u16* Qb = Q + (size_t)bb * S_ * HID_ + (size_t)h * 128;
  const u16* Kb = K + (size_t)bb * S_ * kld + (size_t)h * 128;
  const u16* VTb = VT + (size_t)bh * 128 * S_;
  u16* Ob = O + (size_t)bb * S_ * HID_ + (size_t)h * 128;

  auto stage = [&](int rs, int kvbase) {
#pragma unroll
    for (int pp = 0; pp < 2; ++pp) {
      int kvb = kvbase + pp * 32;
      char* kd = (char*)(Kl + (size_t)(rs * 2 + pp) * 4096);
      char* vd = (char*)(Vl + (size_t)(rs * 2 + pp) * 4096);
#pragma unroll
      for (int c = 0; c < 2; ++c) {
        int s = c * 256 + t;
        int row = s >> 4;
        int ch = (s & 15) ^ (row & 7);
        gload16(&Kb[(size_t)(kvb + row) * kld + ch * 8], kd + s * 16);
      }
#pragma unroll
      for (int c = 0; c < 2; ++c) {
        int s = c * 256 + t;
        int row = s >> 2;
        int ch = (s & 3) ^ ((row >> 1) & 3);
        gload16(&VTb[(size_t)row * S_ + kvb + ch * 8], vd + s * 16);
      }
    }
  };

  u16* Pw = Pl + (size_t)w * 1280;
  const float SCALE = 0.08838834764831845f;

#pragma unroll
  for (int seg = 0; seg < 2; ++seg) {
    const int qt = seg ? (31 - p) : p;
    const int nr = qt + 1;
    const int qrow0 = qt * 64 + sub * 32;

    short8 qf[2][4];
#pragma unroll
    for (int m = 0; m < 2; ++m)
#pragma unroll
      for (int dk = 0; dk < 4; ++dk)
        qf[m][dk] = *(const short8*)&Qb[(size_t)(qrow0 + m * 16 + r16) * HID_ + dk * 32 + q4 * 8];

    f32x4 ao[2][8];
    float mr[2], lr[2];
#pragma unroll
    for (int m = 0; m < 2; ++m) {
#pragma unroll
      for (int dn = 0; dn < 8; ++dn) ao[m][dn] = (f32x4){0.f, 0.f, 0.f, 0.f};
      mr[m] = -1e30f; lr[m] = 0.f;
    }

    stage(0, 0);
    __syncthreads();

    for (int r = 0; r < nr; ++r) {
      const int rs = r & 1;
      if (r + 1 < nr) stage(rs ^ 1, (r + 1) * 64);
      const int kv0 = r * 64 + par * 32;
      const u16* Kbuf = Kl + (size_t)(rs * 2 + par) * 4096;
      const u16* Vbuf = Vl + (size_t)(rs * 2 + par) * 4096;

      if (kv0 <= qrow0 + 31) {
        f32x4 sc[2][2];
#pragma unroll
        for (int m = 0; m < 2; ++m)
#pragma unroll
          for (int n = 0; n < 2; ++n) sc[m][n] = (f32x4){0.f, 0.f, 0.f, 0.f};
#pragma unroll
        for (int dk = 0; dk < 4; ++dk) {
          short8 kf[2];
#pragma unroll
          for (int n = 0; n < 2; ++n) {
            int kr = n * 16 + r16;
            int ba = (kr * 256 + dk * 64 + q4 * 16) ^ ((kr & 7) << 4);
            kf[n] = *(const short8*)((const char*)Kbuf + ba);
          }
          __builtin_amdgcn_s_setprio(1);
#pragma unroll
          for (int n = 0; n < 2; ++n)
#pragma unroll
            for (int m = 0; m < 2; ++m)
              sc[m][n] = __builtin_amdgcn_mfma_f32_16x16x32_bf16(kf[n], qf[m][dk], sc[m][n], 0, 0, 0);
          __builtin_amdgcn_s_setprio(0);
        }
        const bool nm = (kv0 + 31 > qrow0);
#pragma unroll
        for (int m = 0; m < 2; ++m) {
          const int q = qrow0 + m * 16 + r16;
#pragma unroll
          for (int n = 0; n < 2; ++n)
#pragma unroll
            for (int j = 0; j < 4; ++j) {
              float sv = sc[m][n][j] * SCALE;
              if (nm) {
                int kv = kv0 + n * 16 + q4 * 4 + j;
                if (kv > q) sv = -1e30f;
              }
              sc[m][n][j] = sv;
            }
        }
        float tm0[2];
#pragma unroll
        for (int m = 0; m < 2; ++m) {
          float tm = sc[m][0][0];
#pragma unroll
          for (int n = 0; n < 2; ++n)
#pragma unroll
            for (int j = 0; j < 4; ++j) tm = fmaxf(tm, sc[m][n][j]);
          tm = fmaxf(tm, __shfl_xor(tm, 16));
          tm = fmaxf(tm, __shfl_xor(tm, 32));
          tm0[m] = tm;
        }
        float growth = fmaxf(tm0[0] - mr[0], tm0[1] - mr[1]);
        if (!__all(growth <= 8.0f)) {
#pragma unroll
          for (int m = 0; m < 2; ++m) {
            float mnew = fmaxf(mr[m], tm0[m]);
            float fsc = __expf(mr[m] - mnew);
            lr[m] *= fsc; mr[m] = mnew;
#pragma unroll
            for (int dn = 0; dn < 8; ++dn) ao[m][dn] *= fsc;
          }
        }
#pragma unroll
        for (int m = 0; m < 2; ++m) {
          float ps = 0.f;
#pragma unroll
          for (int n = 0; n < 2; ++n)
#pragma unroll
            for (int j = 0; j < 4; ++j) {
              float pv = __expf(sc[m][n][j] - mr[m]);
              sc[m][n][j] = pv;
              ps += pv;
            }
          ps += __shfl_xor(ps, 16);
          ps += __shfl_xor(ps, 32);
          lr[m] += ps;
        }
#pragma unroll
        for (int m = 0; m < 2; ++m)
#pragma unroll
          for (int n = 0; n < 2; ++n) {
            u32 lo, hi;
            asm("v_cvt_pk_bf16_f32 %0, %1, %2" : "=v"(lo) : "v"(sc[m][n][0]), "v"(sc[m][n][1]));
            asm("v_cvt_pk_bf16_f32 %0, %1, %2" : "=v"(hi) : "v"(sc[m][n][2]), "v"(sc[m][n][3]));
            u32x2 pr; pr.x = lo; pr.y = hi;
            int ba = (m * 16 + r16) * 80 + n * 32 + q4 * 8;
            *(u32x2*)((char*)Pw + ba) = pr;
          }
        short8 pb[2];
#pragma unroll
        for (int m = 0; m < 2; ++m)
          pb[m] = *(const short8*)((const char*)Pw + (m * 16 + r16) * 80 + q4 * 16);
        __builtin_amdgcn_s_setprio(1);
#pragma unroll
        for (int dn = 0; dn < 8; ++dn) {
          int d = dn * 16 + r16;
          int bv = d * 64 + ((q4 ^ ((d >> 1) & 3)) * 16);
          short8 vf = *(const short8*)((const char*)Vbuf + bv);
#pragma unroll
          for (int m = 0; m < 2; ++m)
            ao[m][dn] = __builtin_amdgcn_mfma_f32_16x16x32_bf16(vf, pb[m], ao[m][dn], 0, 0, 0);
        }
        __builtin_amdgcn_s_setprio(0);
      }
      __syncthreads();
    }

    {
      float* exb = ex + (size_t)sub * 4352 + (size_t)lane * 68;
      if (par == 1) {
#pragma unroll
        for (int m = 0; m < 2; ++m)
#pragma unroll
          for (int dn = 0; dn < 8; ++dn)
            *(f32x4*)(exb + m * 32 + dn * 4) = ao[m][dn];
        exb[64] = mr[0]; exb[65] = mr[1]; exb[66] = lr[0]; exb[67] = lr[1];
      }
      __syncthreads();
      if (par == 0) {
#pragma unroll
        for (int m = 0; m < 2; ++m) {
          float mB = exb[64 + m], lB = exb[66 + m];
          float mx = fmaxf(mr[m], mB);
          float wA = __expf(mr[m] - mx), wB = __expf(mB - mx);
          float inv = 1.f / (lr[m] * wA + lB * wB);
          const int q = qrow0 + m * 16 + r16;
#pragma unroll
          for (int dn = 0; dn < 8; ++dn) {
            f32x4 ob = *(const f32x4*)(exb + m * 32 + dn * 4);
            u16x4 o;
#pragma unroll
            for (int j = 0; j < 4; ++j) o[j] = f2bf((ao[m][dn][j] * wA + ob[j] * wB) * inv);
            *(u16x4*)&Ob[(size_t)q * HID_ + dn * 16 + q4 * 4] = o;
          }
        }
      }
      __syncthreads();
    }
  }
}

// ---------------- host launch ----------------
extern "C" void kernel_launch(void* const* d_in, const int* in_sizes, int n_in,
                              void* d_out, int out_size, void* d_ws, size_t ws_size,
                              hipStream_t stream) {
  (void)in_sizes; (void)n_in; (void)out_size; (void)ws_size;
  const float* x     = (const float*)d_in[0];
  const float* W_dkv = (const float*)d_in[2];
  const float* b_dkv = (const float*)d_in[3];
  const float* W_uk  = (const float*)d_in[4];
  const float* b_uk  = (const float*)d_in[5];
  const float* W_uv  = (const float*)d_in[6];
  const float* b_uv  = (const float*)d_in[7];
  const float* W_dq  = (const float*)d_in[8];
  const float* b_dq  = (const float*)d_in[9];
  const float* W_uq  = (const float*)d_in[10];
  const float* b_uq  = (const float*)d_in[11];
  const float* W_o   = (const float*)d_in[12];
  const float* b_o   = (const float*)d_in[13];
  float* out = (float*)d_out;

  char* ws = (char*)d_ws;
  size_t off = 0;
  auto carve = [&](size_t bytes) { void* p = ws + off; off += (bytes + 255) & ~(size_t)255; return p; };
  u16* xb     = (u16*)carve((size_t)BS_ * 2048 * 2);      // reused as VT after GEMM1
  u16* WdkvqT = (u16*)carve((size_t)2048 * 2048 * 2);
  u16* WukvT  = (u16*)carve((size_t)4096 * 512 * 2);
  u16* WuqT   = (u16*)carve((size_t)2048 * 1536 * 2);
  u16* WoT    = (u16*)carve((size_t)2048 * 2048 * 2);
  u16* kvq1   = (u16*)carve((size_t)BS_ * 2048 * 2);
  u16* kbuf   = (u16*)carve((size_t)BS_ * 2048 * 2);
  u16* qb     = (u16*)carve((size_t)BS_ * 2048 * 2);
  u16* aob    = (u16*)carve((size_t)BS_ * 2048 * 2);
  float* cs   = (float*)carve((size_t)2048 * 64 * 2 * 4);
  float* bc1  = (float*)carve((size_t)2048 * 4);
  float* bc2  = (float*)carve((size_t)4096 * 4);
  u16* VT     = xb;   // xb dead after GEMM1; V^T [32][128][2048]

  prep<<<dim3(12056), 256, 0, stream>>>(x, xb, W_dkv, W_dq, W_uk, W_uv, W_uq, W_o,
                                        WdkvqT, WukvT, WuqT, WoT,
                                        b_dkv, b_dq, b_uk, b_uv, cs, bc1, bc2);

  // GEMM1: x @ {W_dkv|W_dq} -> kvq1
  gemm_bt<0><<<dim3(2048 / 128, BS_ / 128), 256, 0, stream>>>(xb, 2048, WdkvqT, bc1, kvq1, BS_, 2048, 2048);

  // GEMM2+GEMM3 merged (contiguous long-first grid, dbuf K-loop)
  gemm23<<<dim3(1536), 256, 0, stream>>>(kvq1, WukvT, WuqT, bc2, b_uq, cs, kbuf, VT, qb);

  attn_kernel<<<dim3(512), 256, 0, stream>>>(qb, kbuf, 2048, VT, aob);

  // GEMM4: attn_out @ W_o -> out (fp32)
  gemm_bt<1><<<dim3(2048 / 128, BS_ / 128), 256, 0, stream>>>(aob, 2048, WoT, b_o, out, BS_, 2048, 2048);
}